// Round 1
// baseline (102.498 us; speedup 1.0000x reference)
//
#include <hip/hip_runtime.h>

#define DIM   1024
#define NEXP  20
#define NFRQ  3000
#define TOPK  5
#define BATCH 64

// One block per batch row, 64 lanes. Lanes 0..19 each compute one logit
// (dot over 1024 dims), then lane 0 does a serial stable top-5 argmax
// (strict > == first-occurrence tie-break, matching jax.lax.top_k).
// Softmax is monotonic -> top-k on logits == top-k on probs.
__global__ void router_topk_kernel(const float* __restrict__ cls,
                                   const float* __restrict__ W,
                                   const float* __restrict__ bias,
                                   int* __restrict__ expert_out) {
    const int row  = blockIdx.x;   // 0..63
    const int lane = threadIdx.x;  // 0..63

    __shared__ float logits[NEXP];

    if (lane < NEXP) {
        float acc = bias[lane];
        const float* x = cls + (size_t)row * DIM;
        #pragma unroll 8
        for (int d = 0; d < DIM; ++d) {
            acc += x[d] * W[(size_t)d * NEXP + lane];
        }
        logits[lane] = acc;
    }
    __syncthreads();

    if (lane == 0) {
        bool used[NEXP];
        #pragma unroll
        for (int e = 0; e < NEXP; ++e) used[e] = false;
        for (int k = 0; k < TOPK; ++k) {
            int best = 0;
            float bv = -INFINITY;
            for (int e = 0; e < NEXP; ++e) {
                if (!used[e] && logits[e] > bv) { bv = logits[e]; best = e; }
            }
            used[best] = true;
            expert_out[row * TOPK + k] = best;
        }
    }
}

// grid = (ceil(NFRQ/256), BATCH*TOPK). Each thread writes one 1.0f.
__global__ void scatter_ones_kernel(const int* __restrict__ expert_idx,
                                    const int* __restrict__ list_indices,
                                    float* __restrict__ out) {
    const int f  = blockIdx.x * blockDim.x + threadIdx.x;
    const int bk = blockIdx.y;                 // 0 .. BATCH*TOPK-1
    if (f >= NFRQ) return;
    const int b = bk / TOPK;
    const int e = expert_idx[bk];              // broadcast within block (L2/L1 hit)
    const int col = list_indices[(size_t)e * NFRQ + f];   // coalesced over f
    out[(size_t)b * (size_t)(DIM * DIM) + col] = 1.0f;    // random 4B store
}

extern "C" void kernel_launch(void* const* d_in, const int* in_sizes, int n_in,
                              void* d_out, int out_size, void* d_ws, size_t ws_size,
                              hipStream_t stream) {
    const float* cls          = (const float*)d_in[0];  // [64,1024]
    const float* W            = (const float*)d_in[1];  // [1024,20]
    const float* bias         = (const float*)d_in[2];  // [20]
    const int*   list_indices = (const int*)d_in[3];    // [20,3000]
    float*       out          = (float*)d_out;          // [64,1024,1024]

    int* expert_idx = (int*)d_ws;                        // 64*5 ints

    // 1) router + top-5 (tiny)
    router_topk_kernel<<<dim3(BATCH), dim3(64), 0, stream>>>(cls, W, bias, expert_idx);

    // 2) zero the full 256 MB output
    hipMemsetAsync(d_out, 0, (size_t)out_size * sizeof(float), stream);

    // 3) scatter 960K ones
    dim3 grid((NFRQ + 255) / 256, BATCH * TOPK);
    scatter_ones_kernel<<<grid, dim3(256), 0, stream>>>(expert_idx, list_indices, out);
}